// Round 3
// baseline (107.323 us; speedup 1.0000x reference)
//
#include <hip/hip_runtime.h>

// Pixel shuffle (depth-to-space), r=2:
//   out[b, x, y, c] = in[b, x>>1, y>>1, ((y&1)*2 + (x&1))*16 + c]
// Input  [16, 256, 256, 64] f32, Output [16, 512, 512, 16] f32.
//
// INPUT-indexed, grid-stride UNROLLED x4 for memory-level parallelism:
// 4 independent fully-coalesced loads in flight before the stores, hiding
// ~900-cycle HBM latency better than 1 load/iter. Each access keeps the
// lane-contiguous layout (reads: 1KB/wave contiguous; writes: full
// 128B-line segments). Nontemporal: strictly streaming.

typedef float f4 __attribute__((ext_vector_type(4)));

__device__ __forceinline__ int out_index(int i4) {
    int c4  = i4 & 3;          // float4 within 16-float sub-chunk
    int sub = (i4 >> 2) & 3;   // 2*j + i
    int pix = i4 >> 4;         // (b, h, w)
    int w = pix & 255;
    int h = (pix >> 8) & 255;
    int b = pix >> 16;
    int i = sub & 1;
    int j = sub >> 1;
    int x = (h << 1) | i;      // output row
    int y = (w << 1) | j;      // output col
    return (((((b << 9) | x) << 9) | y) << 2) | c4;
}

__global__ __launch_bounds__(256) void Conv2DSubPixel_44032004718623_kernel(
    const f4* __restrict__ in, f4* __restrict__ out, int n4) {
    int stride = gridDim.x * blockDim.x;
    int tid = blockIdx.x * blockDim.x + threadIdx.x;
    int i4 = tid;
    // unrolled-by-4 main loop (n4 = 2^24, stride = 2^19 -> exact, no tail)
    for (; i4 + 3 * stride < n4; i4 += 4 * stride) {
        int a0 = i4, a1 = i4 + stride, a2 = i4 + 2 * stride, a3 = i4 + 3 * stride;
        f4 v0 = __builtin_nontemporal_load(&in[a0]);
        f4 v1 = __builtin_nontemporal_load(&in[a1]);
        f4 v2 = __builtin_nontemporal_load(&in[a2]);
        f4 v3 = __builtin_nontemporal_load(&in[a3]);
        __builtin_nontemporal_store(v0, &out[out_index(a0)]);
        __builtin_nontemporal_store(v1, &out[out_index(a1)]);
        __builtin_nontemporal_store(v2, &out[out_index(a2)]);
        __builtin_nontemporal_store(v3, &out[out_index(a3)]);
    }
    // tail (empty for the benched shape, kept for generality)
    for (; i4 < n4; i4 += stride) {
        f4 v = __builtin_nontemporal_load(&in[i4]);
        __builtin_nontemporal_store(v, &out[out_index(i4)]);
    }
}

extern "C" void kernel_launch(void* const* d_in, const int* in_sizes, int n_in,
                              void* d_out, int out_size, void* d_ws, size_t ws_size,
                              hipStream_t stream) {
    const f4* in = (const f4*)d_in[0];
    f4* out = (f4*)d_out;
    int n4 = out_size / 4;  // 16,777,216 float4s
    dim3 block(256);
    dim3 grid(2048);        // 8 blocks/CU; 32 elems/thread, 8 unrolled iters
    hipLaunchKernelGGL(Conv2DSubPixel_44032004718623_kernel, grid, block, 0,
                       stream, in, out, n4);
}

// Round 4
// 87.967 us; speedup vs baseline: 1.2200x; 1.2200x over previous
//
#include <hip/hip_runtime.h>

// Pixel shuffle (depth-to-space), r=2:
//   out[b, x, y, c] = in[b, x>>1, y>>1, ((y&1)*2 + (x&1))*16 + c]
// Input  [16, 256, 256, 64] f32, Output [16, 512, 512, 16] f32.
//
// INPUT-indexed, BLOCK-CONTIGUOUS unroll x4:
// each block handles a contiguous 1024-float4 (16 KB) chunk per outer
// iteration; the 4 unrolled accesses are base + k*256 + tid -> each a
// fully-coalesced block-wide 4 KB access, all within the same 16 KB
// region (DRAM page locality preserved, unlike the strided unroll which
// spread them 8 MB apart and regressed). 4 loads in flight per thread.
// Nontemporal: strictly streaming.

typedef float f4 __attribute__((ext_vector_type(4)));

__device__ __forceinline__ int out_index(int i4) {
    int c4  = i4 & 3;          // float4 within 16-float sub-chunk
    int sub = (i4 >> 2) & 3;   // 2*j + i
    int pix = i4 >> 4;         // (b, h, w)
    int w = pix & 255;
    int h = (pix >> 8) & 255;
    int b = pix >> 16;
    int i = sub & 1;
    int j = sub >> 1;
    int x = (h << 1) | i;      // output row
    int y = (w << 1) | j;      // output col
    return (((((b << 9) | x) << 9) | y) << 2) | c4;
}

__global__ __launch_bounds__(256) void Conv2DSubPixel_44032004718623_kernel(
    const f4* __restrict__ in, f4* __restrict__ out, int n4) {
    const int CHUNK = 256 * 4;                     // float4s per block per iter
    int gstride = gridDim.x * CHUNK;               // 2048*1024 = 2^21
    for (int base = blockIdx.x * CHUNK + threadIdx.x; base + 3 * 256 < n4;
         base += gstride) {
        int a0 = base;
        int a1 = base + 256;
        int a2 = base + 512;
        int a3 = base + 768;
        f4 v0 = __builtin_nontemporal_load(&in[a0]);
        f4 v1 = __builtin_nontemporal_load(&in[a1]);
        f4 v2 = __builtin_nontemporal_load(&in[a2]);
        f4 v3 = __builtin_nontemporal_load(&in[a3]);
        __builtin_nontemporal_store(v0, &out[out_index(a0)]);
        __builtin_nontemporal_store(v1, &out[out_index(a1)]);
        __builtin_nontemporal_store(v2, &out[out_index(a2)]);
        __builtin_nontemporal_store(v3, &out[out_index(a3)]);
    }
}

extern "C" void kernel_launch(void* const* d_in, const int* in_sizes, int n_in,
                              void* d_out, int out_size, void* d_ws, size_t ws_size,
                              hipStream_t stream) {
    const f4* in = (const f4*)d_in[0];
    f4* out = (f4*)d_out;
    int n4 = out_size / 4;  // 16,777,216 float4s (2^24)
    dim3 block(256);
    dim3 grid(2048);        // covers 2^21 float4s/iter -> 8 outer iterations
    hipLaunchKernelGGL(Conv2DSubPixel_44032004718623_kernel, grid, block, 0,
                       stream, in, out, n4);
}